// Round 5
// baseline (205.788 us; speedup 1.0000x reference)
//
#include <hip/hip_runtime.h>

#define NF   20000
#define NALL 60000
#define NE   640000
#define DD   128
#define AA   64

typedef __attribute__((ext_vector_type(8))) short short8;
typedef __attribute__((ext_vector_type(4))) float f32x4;

__device__ __forceinline__ unsigned short f2b(float x) {
    unsigned int u = __float_as_uint(x);
    return (unsigned short)((u + 0x7FFFu + ((u >> 16) & 1u)) >> 16);  // RNE
}
__device__ __forceinline__ float b2f(unsigned short v) {
    return __uint_as_float(((unsigned int)v) << 16);
}
__device__ __forceinline__ short8 pack8(float4 a, float4 b) {
    short8 r;
    r[0]=(short)f2b(a.x); r[1]=(short)f2b(a.y); r[2]=(short)f2b(a.z); r[3]=(short)f2b(a.w);
    r[4]=(short)f2b(b.x); r[5]=(short)f2b(b.y); r[6]=(short)f2b(b.z); r[7]=(short)f2b(b.w);
    return r;
}

// ---- K1: fused conv+proj. Loads fp32 embs, converts (writes embB bf16),
// computes P1 = feat@W1+bias, P2 = [feat;hid]@W2 (bf16) via MFMA. W from fp32 on the fly.
__global__ __launch_bounds__(256) void embproj_kernel(
    const float* __restrict__ featEmb, const float* __restrict__ hidEmb,
    const float* __restrict__ wK, const float* __restrict__ bias,
    unsigned short* __restrict__ embB,
    unsigned short* __restrict__ P1b, unsigned short* __restrict__ P2b)
{
    const int wave = threadIdx.x >> 6, lane = threadIdx.x & 63;
    const int rt = blockIdx.x * 4 + wave;
    if (rt >= NALL / 16) return;
    const int row0 = rt * 16;
    const int m = lane & 15, quad = lane >> 4;

    const int row = row0 + m;   // NF % 16 == 0: no tile straddles the feat/hid boundary
    const float* src = (row < NF) ? featEmb + (size_t)row * DD
                                  : hidEmb + (size_t)(row - NF) * DD;
    short8 afr[4];
    #pragma unroll
    for (int kc = 0; kc < 4; ++kc) {
        float4 a0 = *(const float4*)&src[kc * 32 + quad * 8];
        float4 a1 = *(const float4*)&src[kc * 32 + quad * 8 + 4];
        afr[kc] = pack8(a0, a1);
        *(short8*)&embB[(size_t)row * DD + kc * 32 + quad * 8] = afr[kc];
    }

    const float* W2 = wK + DD * AA;   // rows 128..255 of w_kernel
    #pragma unroll
    for (int nt = 0; nt < 4; ++nt) {
        f32x4 acc = {0.f, 0.f, 0.f, 0.f};
        #pragma unroll
        for (int kc = 0; kc < 4; ++kc) {
            short8 bfr;
            #pragma unroll
            for (int j = 0; j < 8; ++j)
                bfr[j] = (short)f2b(W2[(kc * 32 + quad * 8 + j) * AA + nt * 16 + m]);
            acc = __builtin_amdgcn_mfma_f32_16x16x32_bf16(afr[kc], bfr, acc, 0, 0, 0);
        }
        #pragma unroll
        for (int r = 0; r < 4; ++r)   // C/D: col=lane&15, row=quad*4+r
            P2b[(size_t)(row0 + quad * 4 + r) * AA + nt * 16 + m] = f2b(acc[r]);
    }
    if (row0 < NF) {
        #pragma unroll
        for (int nt = 0; nt < 4; ++nt) {
            f32x4 acc = {0.f, 0.f, 0.f, 0.f};
            #pragma unroll
            for (int kc = 0; kc < 4; ++kc) {
                short8 bfr;
                #pragma unroll
                for (int j = 0; j < 8; ++j)
                    bfr[j] = (short)f2b(wK[(kc * 32 + quad * 8 + j) * AA + nt * 16 + m]);
                acc = __builtin_amdgcn_mfma_f32_16x16x32_bf16(afr[kc], bfr, acc, 0, 0, 0);
            }
            const float bv = bias[nt * 16 + m];
            #pragma unroll
            for (int r = 0; r < 4; ++r)
                P1b[(size_t)(row0 + quad * 4 + r) * AA + nt * 16 + m] = f2b(acc[r] + bv);
        }
    }
}

// ---- K2: rowptr[f] = lower_bound(cp, f). Boundary scatter, cp sorted.
__global__ __launch_bounds__(256) void rowptr_kernel(
    const int* __restrict__ cp, int* __restrict__ rowptr)
{
    const int e = blockIdx.x * 256 + threadIdx.x;
    const int cur = cp[e];
    const int prev = (e == 0) ? -1 : cp[e - 1];
    for (int f = prev + 1; f <= cur; ++f) rowptr[f] = e;
    if (e == NE - 1)
        for (int f = cur + 1; f <= NF; ++f) rowptr[f] = NE;
}

// ---- K3: fused scoring + softmax + context -> ctx [NF][128] row-major.
// One independent wave per feature, 32-edge chunks. Per chunk:
//   1 coalesced fci load (lane-indexed; fci is SEQUENTIAL per feature) makes
//   ALL gather addresses known at once -> flat burst of ~38 independent loads:
//   4x P2 uint4 (issued FIRST: oldest in vmcnt queue -> scoring can start
//   without draining embB loads) then 32x embB u32 (one full 256B row per
//   instruction). Invalid tail lanes get corr=0 -> contribute exactly 0.
// Scoring: part = Sum(u) - 2*Sum(r*u), r = 1/(exp2(x*2log2e)+1)  (== u.tanh(x))
// No LDS; scores broadcast via shfl.
__global__ __launch_bounds__(256) void scorectx_kernel(
    const unsigned short* __restrict__ embB,
    const unsigned short* __restrict__ P1b, const unsigned short* __restrict__ P2b,
    const float* __restrict__ uK, const float* __restrict__ corr,
    const int* __restrict__ rowptr, const int* __restrict__ fci,
    unsigned short* __restrict__ ctx)
{
    const int lane = threadIdx.x & 63;
    const int wave = threadIdx.x >> 6;       // 0..3
    const int f = blockIdx.x * 4 + wave;     // 5000 blocks * 4 waves = 20000 = NF

    const int c = lane & 7, g = lane >> 3;   // col-octet c, edge-slot g
    float m2u[8]; float suml = 0.f;
    #pragma unroll
    for (int k = 0; k < 8; ++k) { const float u = uK[c * 8 + k]; m2u[k] = -2.f * u; suml += u; }

    const int start = rowptr[f], end = rowptr[f + 1];

    float p1v[8];   // P1 row, once per feature
    {
        uint4 qv = *(const uint4*)&P1b[(size_t)f * AA + c * 8];
        unsigned int qq[4] = {qv.x, qv.y, qv.z, qv.w};
        #pragma unroll
        for (int k = 0; k < 4; ++k) {
            p1v[2*k]   = b2f((unsigned short)(qq[k] & 0xFFFF));
            p1v[2*k+1] = b2f((unsigned short)(qq[k] >> 16));
        }
    }

    float acc0 = 0.f, acc1 = 0.f, den = 0.f;
    const float C2L2E = 2.8853900817779268f;   // 2*log2(e)

    for (int cb = start; cb < end; cb += 32) {
        const int n = min(32, end - cb);
        // one coalesced load gets all 32 edge indices (both half-waves same line)
        const int le = lane & 31;
        const int ce = (le < n) ? (cb + le) : (end - 1);   // clamped: stays in-bounds
        const int idxl = fci[ce];
        const float crl = (le < n) ? corr[ce] : 0.f;       // invalid -> score 0

        // P2 gathers FIRST (oldest in queue -> usable before embB retires)
        uint4 q[4];
        #pragma unroll
        for (int eb = 0; eb < 4; ++eb) {
            if (eb * 8 < n) {
                const int ig = __shfl(idxl, eb * 8 + g);
                q[eb] = *(const uint4*)&P2b[(size_t)ig * AA + c * 8];
            } else q[eb] = (uint4){0u, 0u, 0u, 0u};
        }
        // embB gathers: 32 independent full-row loads (u32/lane = 256B/row)
        unsigned int vv[32];
        #pragma unroll
        for (int jb = 0; jb < 4; ++jb) {
            if (jb * 8 < n) {
                #pragma unroll
                for (int j = 0; j < 8; ++j) {
                    const int ij = __shfl(idxl, jb * 8 + j);
                    vv[jb*8+j] = *(const unsigned int*)&embB[(size_t)ij * DD + lane * 2];
                }
            }
        }
        #pragma unroll
        for (int eb = 0; eb < 4; ++eb) {
            if (eb * 8 < n) {
                unsigned int qq[4] = {q[eb].x, q[eb].y, q[eb].z, q[eb].w};
                float part = suml;
                #pragma unroll
                for (int k = 0; k < 4; ++k) {
                    const float x0 = p1v[2*k]   + b2f((unsigned short)(qq[k] & 0xFFFF));
                    const float x1 = p1v[2*k+1] + b2f((unsigned short)(qq[k] >> 16));
                    const float r0 = __builtin_amdgcn_rcpf(exp2f(x0 * C2L2E) + 1.f);
                    const float r1 = __builtin_amdgcn_rcpf(exp2f(x1 * C2L2E) + 1.f);
                    part = fmaf(r0, m2u[2*k],   part);
                    part = fmaf(r1, m2u[2*k+1], part);
                }
                part += __shfl_xor(part, 1);
                part += __shfl_xor(part, 2);
                part += __shfl_xor(part, 4);
                const float crs = __shfl(crl, eb * 8 + g);
                const float s = __expf(part) * crs;
                #pragma unroll
                for (int j = 0; j < 8; ++j) {
                    const float sj = __shfl(s, j * 8);   // edge eb*8+j (octet j)
                    const unsigned int v = vv[eb*8+j];
                    acc0 = fmaf(sj, b2f((unsigned short)(v & 0xFFFF)), acc0);
                    acc1 = fmaf(sj, b2f((unsigned short)(v >> 16)),    acc1);
                    den += sj;
                }
            }
        }
    }
    const float inv = (den != 0.f) ? 1.f / den : 0.f;
    // dims {2*lane, 2*lane+1} packed -> 64 lanes x u32 = one full 256B line
    *(unsigned int*)&ctx[(size_t)f * DD + 2 * lane] =
        ((unsigned int)f2b(acc1 * inv) << 16) | f2b(acc0 * inv);
}

// ---- K4: transpose ctx [NF][128] -> ctxT [128][NF] (bf16), full-line I/O both
// sides. Also zeroes `out` (folds the memset dispatch away; runs before outmm).
__global__ __launch_bounds__(256) void transpose_kernel(
    const unsigned short* __restrict__ ctx, unsigned short* __restrict__ ctxT,
    float* __restrict__ out)
{
    __shared__ unsigned int tile[64 * 33];   // [dpair][feat]: lo16=row 2d, hi16=row 2d+1
    const int t = threadIdx.x;
    const int gid = blockIdx.x * 256 + t;
    if (gid < (256 * DD) / 4) {              // 8192 float4 = 256x128 out zero-init
        f32x4 z = {0.f, 0.f, 0.f, 0.f};
        *(f32x4*)&out[gid * 4] = z;
    }
    const int f0 = blockIdx.x * 32;
    const int fl = t >> 3, db = t & 7;       // feature-local 0..31, dim-block (16 dims)
    const unsigned int* src = (const unsigned int*)&ctx[(size_t)(f0 + fl) * DD + db * 16];
    uint4 q0 = *(const uint4*)src;           // dims db*16+0..7 (u32 j: dims 2j,2j+1)
    uint4 q1 = *(const uint4*)(src + 4);     // dims db*16+8..15
    unsigned int w[8] = {q0.x, q0.y, q0.z, q0.w, q1.x, q1.y, q1.z, q1.w};
    #pragma unroll
    for (int j = 0; j < 8; ++j)
        tile[(db * 8 + j) * 33 + fl] = w[j];
    __syncthreads();

    const int r = t >> 1, side = t & 1;      // row 0..127, 16-feature half
    const int dpair = r >> 1, odd = r & 1;
    unsigned int o[8];
    #pragma unroll
    for (int i = 0; i < 8; ++i) {
        const int fo = side * 16 + i * 2;
        const unsigned int v0 = tile[dpair * 33 + fo];
        const unsigned int v1 = tile[dpair * 33 + fo + 1];
        o[i] = odd ? ((v1 & 0xFFFF0000u) | (v0 >> 16))
                   : ((v1 << 16) | (v0 & 0xFFFFu));
    }
    uint4 a = {o[0], o[1], o[2], o[3]}, b = {o[4], o[5], o[6], o[7]};
    *(uint4*)&ctxT[(size_t)r * NF + f0 + side * 16]     = a;
    *(uint4*)&ctxT[(size_t)r * NF + f0 + side * 16 + 8] = b;
}

// ---- K5: out[256,128] = values @ ctx via MFMA; values split hi/lo bf16 (exact).
// kchunks=25 (800 cols each): 5x fewer device-scope atomics than 125-chunk split.
__global__ __launch_bounds__(256) void outmm_kernel(
    const float* __restrict__ values, const unsigned short* __restrict__ ctxT,
    float* __restrict__ out)
{
    const int wave = threadIdx.x >> 6, lane = threadIdx.x & 63;
    const int m = lane & 15, quad = lane >> 4;
    const int mgroup = blockIdx.x & 3, kchunk = blockIdx.x >> 2;
    const int m0 = mgroup * 64 + wave * 16;
    const int k0 = kchunk * 800;

    f32x4 acc[8];
    #pragma unroll
    for (int nt = 0; nt < 8; ++nt) acc[nt] = (f32x4){0.f, 0.f, 0.f, 0.f};

    for (int ks = 0; ks < 25; ++ks) {
        const int kk = k0 + ks * 32 + quad * 8;
        const float* ap = &values[(size_t)(m0 + m) * NF + kk];
        float4 a0 = *(const float4*)ap;
        float4 a1 = *(const float4*)(ap + 4);
        float av[8] = {a0.x, a0.y, a0.z, a0.w, a1.x, a1.y, a1.z, a1.w};
        short8 ahi, alo;
        #pragma unroll
        for (int j = 0; j < 8; ++j) {
            unsigned short hv = f2b(av[j]);
            ahi[j] = (short)hv;
            alo[j] = (short)f2b(av[j] - b2f(hv));
        }
        #pragma unroll
        for (int nt = 0; nt < 8; ++nt) {
            short8 b = *(const short8*)&ctxT[(size_t)(nt * 16 + m) * NF + kk];
            acc[nt] = __builtin_amdgcn_mfma_f32_16x16x32_bf16(ahi, b, acc[nt], 0, 0, 0);
            acc[nt] = __builtin_amdgcn_mfma_f32_16x16x32_bf16(alo, b, acc[nt], 0, 0, 0);
        }
    }
    #pragma unroll
    for (int nt = 0; nt < 8; ++nt)
        #pragma unroll
        for (int r = 0; r < 4; ++r)
            atomicAdd(&out[(size_t)(m0 + quad * 4 + r) * DD + nt * 16 + m], acc[nt][r]);
}

extern "C" void kernel_launch(void* const* d_in, const int* in_sizes, int n_in,
                              void* d_out, int out_size, void* d_ws, size_t ws_size,
                              hipStream_t stream)
{
    const float* values  = (const float*)d_in[0];
    const float* featEmb = (const float*)d_in[1];
    const float* hidEmb  = (const float*)d_in[2];
    const float* wK      = (const float*)d_in[3];
    const float* wB      = (const float*)d_in[4];
    const float* uK      = (const float*)d_in[5];
    const float* corr    = (const float*)d_in[6];
    const int* cp        = (const int*)d_in[7];
    const int* fci       = (const int*)d_in[8];
    float* out = (float*)d_out;

    // ws layout (bytes, 16B-aligned):
    char* ws = (char*)d_ws;
    unsigned short* embB  = (unsigned short*)(ws);                   // 15,360,000
    unsigned short* P1b   = (unsigned short*)(ws + 15360000);        //  2,560,000
    unsigned short* P2b   = (unsigned short*)(ws + 17920000);        //  7,680,000
    unsigned short* ctx   = (unsigned short*)(ws + 25600000);        //  5,120,000
    unsigned short* ctxT  = (unsigned short*)(ws + 30720000);        //  5,120,000
    int*            rowptr= (int*)          (ws + 35840000);         //     80,004  (total ~35.9 MB)

    embproj_kernel  <<<938,  256, 0, stream>>>(featEmb, hidEmb, wK, wB, embB, P1b, P2b);
    rowptr_kernel   <<<2500, 256, 0, stream>>>(cp, rowptr);
    scorectx_kernel <<<5000, 256, 0, stream>>>(embB, P1b, P2b, uK, corr, rowptr, fci, ctx);
    transpose_kernel<<<625,  256, 0, stream>>>(ctx, ctxT, out);
    outmm_kernel    <<<100,  256, 0, stream>>>(values, ctxT, out);
}

// Round 6
// 204.770 us; speedup vs baseline: 1.0050x; 1.0050x over previous
//
#include <hip/hip_runtime.h>

#define NF   20000
#define NALL 60000
#define NE   640000
#define DD   128
#define AA   64

typedef __attribute__((ext_vector_type(8))) short short8;
typedef __attribute__((ext_vector_type(4))) float f32x4;

__device__ __forceinline__ unsigned short f2b(float x) {
    unsigned int u = __float_as_uint(x);
    return (unsigned short)((u + 0x7FFFu + ((u >> 16) & 1u)) >> 16);  // RNE
}
__device__ __forceinline__ float b2f(unsigned short v) {
    return __uint_as_float(((unsigned int)v) << 16);
}
__device__ __forceinline__ short8 pack8(float4 a, float4 b) {
    short8 r;
    r[0]=(short)f2b(a.x); r[1]=(short)f2b(a.y); r[2]=(short)f2b(a.z); r[3]=(short)f2b(a.w);
    r[4]=(short)f2b(b.x); r[5]=(short)f2b(b.y); r[6]=(short)f2b(b.z); r[7]=(short)f2b(b.w);
    return r;
}

// ---- K1: fused conv+proj. Loads fp32 embs, converts (writes embB bf16),
// computes P1 = feat@W1+bias, P2 = [feat;hid]@W2 (bf16) via MFMA. W from fp32 on the fly.
__global__ __launch_bounds__(256) void embproj_kernel(
    const float* __restrict__ featEmb, const float* __restrict__ hidEmb,
    const float* __restrict__ wK, const float* __restrict__ bias,
    unsigned short* __restrict__ embB,
    unsigned short* __restrict__ P1b, unsigned short* __restrict__ P2b)
{
    const int wave = threadIdx.x >> 6, lane = threadIdx.x & 63;
    const int rt = blockIdx.x * 4 + wave;
    if (rt >= NALL / 16) return;
    const int row0 = rt * 16;
    const int m = lane & 15, quad = lane >> 4;

    const int row = row0 + m;   // NF % 16 == 0: no tile straddles the feat/hid boundary
    const float* src = (row < NF) ? featEmb + (size_t)row * DD
                                  : hidEmb + (size_t)(row - NF) * DD;
    short8 afr[4];
    #pragma unroll
    for (int kc = 0; kc < 4; ++kc) {
        float4 a0 = *(const float4*)&src[kc * 32 + quad * 8];
        float4 a1 = *(const float4*)&src[kc * 32 + quad * 8 + 4];
        afr[kc] = pack8(a0, a1);
        *(short8*)&embB[(size_t)row * DD + kc * 32 + quad * 8] = afr[kc];
    }

    const float* W2 = wK + DD * AA;   // rows 128..255 of w_kernel
    #pragma unroll
    for (int nt = 0; nt < 4; ++nt) {
        f32x4 acc = {0.f, 0.f, 0.f, 0.f};
        #pragma unroll
        for (int kc = 0; kc < 4; ++kc) {
            short8 bfr;
            #pragma unroll
            for (int j = 0; j < 8; ++j)
                bfr[j] = (short)f2b(W2[(kc * 32 + quad * 8 + j) * AA + nt * 16 + m]);
            acc = __builtin_amdgcn_mfma_f32_16x16x32_bf16(afr[kc], bfr, acc, 0, 0, 0);
        }
        #pragma unroll
        for (int r = 0; r < 4; ++r)   // C/D: col=lane&15, row=quad*4+r
            P2b[(size_t)(row0 + quad * 4 + r) * AA + nt * 16 + m] = f2b(acc[r]);
    }
    if (row0 < NF) {
        #pragma unroll
        for (int nt = 0; nt < 4; ++nt) {
            f32x4 acc = {0.f, 0.f, 0.f, 0.f};
            #pragma unroll
            for (int kc = 0; kc < 4; ++kc) {
                short8 bfr;
                #pragma unroll
                for (int j = 0; j < 8; ++j)
                    bfr[j] = (short)f2b(wK[(kc * 32 + quad * 8 + j) * AA + nt * 16 + m]);
                acc = __builtin_amdgcn_mfma_f32_16x16x32_bf16(afr[kc], bfr, acc, 0, 0, 0);
            }
            const float bv = bias[nt * 16 + m];
            #pragma unroll
            for (int r = 0; r < 4; ++r)
                P1b[(size_t)(row0 + quad * 4 + r) * AA + nt * 16 + m] = f2b(acc[r] + bv);
        }
    }
}

// ---- K2: rowptr[f] = lower_bound(cp, f). Boundary scatter, cp sorted.
__global__ __launch_bounds__(256) void rowptr_kernel(
    const int* __restrict__ cp, int* __restrict__ rowptr)
{
    const int e = blockIdx.x * 256 + threadIdx.x;
    const int cur = cp[e];
    const int prev = (e == 0) ? -1 : cp[e - 1];
    for (int f = prev + 1; f <= cur; ++f) rowptr[f] = e;
    if (e == NE - 1)
        for (int f = cur + 1; f <= NF; ++f) rowptr[f] = NE;
}

// ---- K3: fused scoring + softmax + context -> ctx [NF][128] row-major.
// One independent wave per feature. 4-STAGE rotating software pipeline over
// 8-edge groups (round-4's proven 2-stage shape, deepened): steady state keeps
// 3 groups' loads (~33 indep loads) in flight under each COMPUTE. Per-stage
// state is small (q:4 + vv:8 + cr:1 VGPRs) so the compiler keeps it resident
// (round-5 lesson: one big vv[32] array gets sunk and serialized).
// Scoring math in exp2 domain: u.tanh(x) summed = suml - 2*Sum(u*r),
// r = 1/(exp2(x*2log2e)+1); final exp folded to exp2. Invalid tail lanes get
// cr=0 -> contribute exactly 0. No LDS; scores broadcast via shfl.
__global__ __launch_bounds__(512) void scorectx_kernel(
    const unsigned short* __restrict__ embB,
    const unsigned short* __restrict__ P1b, const unsigned short* __restrict__ P2b,
    const float* __restrict__ uK, const float* __restrict__ corr,
    const int* __restrict__ rowptr, const int* __restrict__ fci,
    unsigned short* __restrict__ ctx)
{
    const int lane = threadIdx.x & 63;
    const int wave = threadIdx.x >> 6;       // 0..7
    const int f = blockIdx.x * 8 + wave;     // 2500 blocks * 8 waves = 20000 = NF

    const int c = lane & 7, g = lane >> 3;   // col-octet c, edge-slot g
    const float L2E   = 1.4426950408889634f;
    const float C2L2E = 2.8853900817779268f; // 2*log2(e)
    float m2l[8]; float suml2 = 0.f;
    #pragma unroll
    for (int k = 0; k < 8; ++k) {
        const float u = uK[c * 8 + k];
        m2l[k] = -2.f * L2E * u;
        suml2 += L2E * u;
    }

    const int start = rowptr[f], end = rowptr[f + 1];

    float p1sc[8];   // P1 row * 2log2e, once per feature
    {
        uint4 qv = *(const uint4*)&P1b[(size_t)f * AA + c * 8];
        unsigned int qq[4] = {qv.x, qv.y, qv.z, qv.w};
        #pragma unroll
        for (int k = 0; k < 4; ++k) {
            p1sc[2*k]   = b2f((unsigned short)(qq[k] & 0xFFFF)) * C2L2E;
            p1sc[2*k+1] = b2f((unsigned short)(qq[k] >> 16)) * C2L2E;
        }
    }

    float acc0 = 0.f, acc1 = 0.f, den = 0.f;

    if (start < end) {
        uint4 qA, qB, qC, qD;                       // P2 fragment, my octet's edge
        unsigned int vvA[8], vvB[8], vvC[8], vvD[8];// embB row u32, edges 0..7
        float crA, crB, crC, crD;                   // corr (0 for invalid tail)

        #define PRELOAD(e_, q_, vv_, cr_)                                          \
        {                                                                          \
            const int ee = (e_) + g;                                               \
            const int ec = (ee < end) ? ee : (end - 1);                            \
            const int idx = fci[ec];                                               \
            const float crv = corr[ec];                                            \
            cr_ = (ee < end) ? crv : 0.f;                                          \
            q_ = *(const uint4*)&P2b[(size_t)idx * AA + c * 8];                    \
            _Pragma("unroll")                                                      \
            for (int j = 0; j < 8; ++j) {                                          \
                const int ij = __shfl(idx, j * 8);                                 \
                vv_[j] = *(const unsigned int*)&embB[(size_t)ij * DD + lane * 2];  \
            }                                                                      \
        }

        #define COMPUTE(q_, vv_, cr_)                                              \
        {                                                                          \
            unsigned int qq[4] = {q_.x, q_.y, q_.z, q_.w};                         \
            float part = suml2;                                                    \
            _Pragma("unroll")                                                      \
            for (int k = 0; k < 4; ++k) {                                          \
                const float a0 = fmaf(b2f((unsigned short)(qq[k] & 0xFFFF)), C2L2E, p1sc[2*k]);   \
                const float a1 = fmaf(b2f((unsigned short)(qq[k] >> 16)),    C2L2E, p1sc[2*k+1]); \
                const float r0 = __builtin_amdgcn_rcpf(exp2f(a0) + 1.f);           \
                const float r1 = __builtin_amdgcn_rcpf(exp2f(a1) + 1.f);           \
                part = fmaf(r0, m2l[2*k],   part);                                 \
                part = fmaf(r1, m2l[2*k+1], part);                                 \
            }                                                                      \
            part += __shfl_xor(part, 1);                                           \
            part += __shfl_xor(part, 2);                                           \
            part += __shfl_xor(part, 4);                                           \
            const float s = exp2f(part) * cr_;                                     \
            _Pragma("unroll")                                                      \
            for (int j = 0; j < 8; ++j) {                                          \
                const float sj = __shfl(s, j * 8);                                 \
                const unsigned int v = vv_[j];                                     \
                acc0 = fmaf(sj, b2f((unsigned short)(v & 0xFFFF)), acc0);          \
                acc1 = fmaf(sj, b2f((unsigned short)(v >> 16)),    acc1);          \
                den += sj;                                                         \
            }                                                                      \
        }

        int e = start;
        PRELOAD(e, qA, vvA, crA);
        if (e + 8  < end) PRELOAD(e + 8,  qB, vvB, crB);
        if (e + 16 < end) PRELOAD(e + 16, qC, vvC, crC);
        if (e + 24 < end) PRELOAD(e + 24, qD, vvD, crD);
        for (;;) {
            COMPUTE(qA, vvA, crA);
            if (e + 32 < end) PRELOAD(e + 32, qA, vvA, crA);
            e += 8; if (e >= end) break;
            COMPUTE(qB, vvB, crB);
            if (e + 32 < end) PRELOAD(e + 32, qB, vvB, crB);
            e += 8; if (e >= end) break;
            COMPUTE(qC, vvC, crC);
            if (e + 32 < end) PRELOAD(e + 32, qC, vvC, crC);
            e += 8; if (e >= end) break;
            COMPUTE(qD, vvD, crD);
            if (e + 32 < end) PRELOAD(e + 32, qD, vvD, crD);
            e += 8; if (e >= end) break;
        }
        #undef PRELOAD
        #undef COMPUTE
    }

    const float inv = (den != 0.f) ? 1.f / den : 0.f;
    // dims {2*lane, 2*lane+1} packed -> 64 lanes x u32 = one full 256B line
    *(unsigned int*)&ctx[(size_t)f * DD + 2 * lane] =
        ((unsigned int)f2b(acc1 * inv) << 16) | f2b(acc0 * inv);
}

// ---- K4: transpose ctx [NF][128] -> ctxT [128][NF] (bf16), full-line I/O both
// sides. Also zeroes `out` (folds the memset dispatch away; runs before outmm).
__global__ __launch_bounds__(256) void transpose_kernel(
    const unsigned short* __restrict__ ctx, unsigned short* __restrict__ ctxT,
    float* __restrict__ out)
{
    __shared__ unsigned int tile[64 * 33];   // [dpair][feat]: lo16=row 2d, hi16=row 2d+1
    const int t = threadIdx.x;
    const int gid = blockIdx.x * 256 + t;
    if (gid < (256 * DD) / 4) {              // 8192 float4 = 256x128 out zero-init
        f32x4 z = {0.f, 0.f, 0.f, 0.f};
        *(f32x4*)&out[gid * 4] = z;
    }
    const int f0 = blockIdx.x * 32;
    const int fl = t >> 3, db = t & 7;       // feature-local 0..31, dim-block (16 dims)
    const unsigned int* src = (const unsigned int*)&ctx[(size_t)(f0 + fl) * DD + db * 16];
    uint4 q0 = *(const uint4*)src;           // dims db*16+0..7 (u32 j: dims 2j,2j+1)
    uint4 q1 = *(const uint4*)(src + 4);     // dims db*16+8..15
    unsigned int w[8] = {q0.x, q0.y, q0.z, q0.w, q1.x, q1.y, q1.z, q1.w};
    #pragma unroll
    for (int j = 0; j < 8; ++j)
        tile[(db * 8 + j) * 33 + fl] = w[j];
    __syncthreads();

    const int r = t >> 1, side = t & 1;      // row 0..127, 16-feature half
    const int dpair = r >> 1, odd = r & 1;
    unsigned int o[8];
    #pragma unroll
    for (int i = 0; i < 8; ++i) {
        const int fo = side * 16 + i * 2;
        const unsigned int v0 = tile[dpair * 33 + fo];
        const unsigned int v1 = tile[dpair * 33 + fo + 1];
        o[i] = odd ? ((v1 & 0xFFFF0000u) | (v0 >> 16))
                   : ((v1 << 16) | (v0 & 0xFFFFu));
    }
    uint4 a = {o[0], o[1], o[2], o[3]}, b = {o[4], o[5], o[6], o[7]};
    *(uint4*)&ctxT[(size_t)r * NF + f0 + side * 16]     = a;
    *(uint4*)&ctxT[(size_t)r * NF + f0 + side * 16 + 8] = b;
}

// ---- K5: out[256,128] = values @ ctx via MFMA; values split hi/lo bf16 (exact).
// grid 500 (4 mgroups x 125 kchunks): full-chip occupancy; atomics are cheap
// relative to the underutilization a smaller grid causes (round-5 lesson).
__global__ __launch_bounds__(256) void outmm_kernel(
    const float* __restrict__ values, const unsigned short* __restrict__ ctxT,
    float* __restrict__ out)
{
    const int wave = threadIdx.x >> 6, lane = threadIdx.x & 63;
    const int m = lane & 15, quad = lane >> 4;
    const int mgroup = blockIdx.x & 3, kchunk = blockIdx.x >> 2;
    const int m0 = mgroup * 64 + wave * 16;
    const int k0 = kchunk * 160;

    f32x4 acc[8];
    #pragma unroll
    for (int nt = 0; nt < 8; ++nt) acc[nt] = (f32x4){0.f, 0.f, 0.f, 0.f};

    for (int ks = 0; ks < 5; ++ks) {
        const int kk = k0 + ks * 32 + quad * 8;
        const float* ap = &values[(size_t)(m0 + m) * NF + kk];
        float4 a0 = *(const float4*)ap;
        float4 a1 = *(const float4*)(ap + 4);
        float av[8] = {a0.x, a0.y, a0.z, a0.w, a1.x, a1.y, a1.z, a1.w};
        short8 ahi, alo;
        #pragma unroll
        for (int j = 0; j < 8; ++j) {
            unsigned short hv = f2b(av[j]);
            ahi[j] = (short)hv;
            alo[j] = (short)f2b(av[j] - b2f(hv));
        }
        #pragma unroll
        for (int nt = 0; nt < 8; ++nt) {
            short8 b = *(const short8*)&ctxT[(size_t)(nt * 16 + m) * NF + kk];
            acc[nt] = __builtin_amdgcn_mfma_f32_16x16x32_bf16(ahi, b, acc[nt], 0, 0, 0);
            acc[nt] = __builtin_amdgcn_mfma_f32_16x16x32_bf16(alo, b, acc[nt], 0, 0, 0);
        }
    }
    #pragma unroll
    for (int nt = 0; nt < 8; ++nt)
        #pragma unroll
        for (int r = 0; r < 4; ++r)
            atomicAdd(&out[(size_t)(m0 + quad * 4 + r) * DD + nt * 16 + m], acc[nt][r]);
}

extern "C" void kernel_launch(void* const* d_in, const int* in_sizes, int n_in,
                              void* d_out, int out_size, void* d_ws, size_t ws_size,
                              hipStream_t stream)
{
    const float* values  = (const float*)d_in[0];
    const float* featEmb = (const float*)d_in[1];
    const float* hidEmb  = (const float*)d_in[2];
    const float* wK      = (const float*)d_in[3];
    const float* wB      = (const float*)d_in[4];
    const float* uK      = (const float*)d_in[5];
    const float* corr    = (const float*)d_in[6];
    const int* cp        = (const int*)d_in[7];
    const int* fci       = (const int*)d_in[8];
    float* out = (float*)d_out;

    // ws layout (bytes, 16B-aligned):
    char* ws = (char*)d_ws;
    unsigned short* embB  = (unsigned short*)(ws);                   // 15,360,000
    unsigned short* P1b   = (unsigned short*)(ws + 15360000);        //  2,560,000
    unsigned short* P2b   = (unsigned short*)(ws + 17920000);        //  7,680,000
    unsigned short* ctx   = (unsigned short*)(ws + 25600000);        //  5,120,000
    unsigned short* ctxT  = (unsigned short*)(ws + 30720000);        //  5,120,000
    int*            rowptr= (int*)          (ws + 35840000);         //     80,004  (total ~35.9 MB)

    embproj_kernel  <<<938,  256, 0, stream>>>(featEmb, hidEmb, wK, wB, embB, P1b, P2b);
    rowptr_kernel   <<<2500, 256, 0, stream>>>(cp, rowptr);
    scorectx_kernel <<<2500, 512, 0, stream>>>(embB, P1b, P2b, uK, corr, rowptr, fci, ctx);
    transpose_kernel<<<625,  256, 0, stream>>>(ctx, ctxT, out);
    outmm_kernel    <<<500,  256, 0, stream>>>(values, ctxT, out);
}